// Round 15
// baseline (833.672 us; speedup 1.0000x reference)
//
#include <hip/hip_runtime.h>
#include <math.h>

typedef _Float16 f16;
typedef _Float16 f16x8 __attribute__((ext_vector_type(8)));
typedef float f32x4 __attribute__((ext_vector_type(4)));

namespace {

constexpr int NT = 512;     // 8 waves = 2 row-halves x 4 col-quarters (64 rows x 64 cols each)
constexpr int M  = 128;     // agents per block: 256 blocks = 1 per CU, single pass
constexpr int HORIZON = 64;

// packed f16 weight layout in d_ws (f16 units); per-chunk fragment order [q][col][j]
constexpr int W2H = 0;        // 65536 f16
constexpr int W2L = 65536;
constexpr int W3H = 131072;
constexpr int W3L = 196608;
constexpr int W1H = 262144;   // 8192 f16 (K padded 13->32)
constexpr int W1L = 270336;   // total 278528 f16 = 544 KB

// ---------------- weight pre-split + pre-pack (once per launch) ----------------
__global__ void prep_kernel(const float* __restrict__ w1, const float* __restrict__ w2,
                            const float* __restrict__ w3, f16* __restrict__ out)
{
    int tid = blockIdx.x * blockDim.x + threadIdx.x;   // 544*256 = 139264 exact
    float v; int hi, lo;
    if (tid < 65536) {          // w2
        int kc = tid >> 13, e2 = tid & 8191;
        int qq = e2 >> 11, col = (e2 >> 3) & 255, j = e2 & 7;
        v = w2[(kc*32 + qq*8 + j)*256 + col];
        hi = W2H + tid; lo = W2L + tid;
    } else if (tid < 131072) {  // w3
        int e = tid - 65536;
        int kc = e >> 13, e2 = e & 8191;
        int qq = e2 >> 11, col = (e2 >> 3) & 255, j = e2 & 7;
        v = w3[(kc*32 + qq*8 + j)*256 + col];
        hi = W3H + e; lo = W3L + e;
    } else {                    // w1, zero-padded to k=32
        int e = tid - 131072;
        int qq = e >> 11, col = (e >> 3) & 255, j = e & 7;
        int k = qq*8 + j;
        v = (k < 13) ? w1[k*256 + col] : 0.f;
        hi = W1H + e; lo = W1L + e;
    }
    f16 h = (f16)v;
    out[hi] = h;
    out[lo] = (f16)(v - (float)h);   // exact weight residual (used by w1 path only now)
}

// 3-term: exact A (hi+lo) x exact B (hi+lo), used for obs x w1 only
__device__ __forceinline__ void mfma3(f32x4& acc, f16x8 ah, f16x8 al, f16x8 bh, f16x8 bl)
{
    acc = __builtin_amdgcn_mfma_f32_16x16x32_f16(ah, bh, acc, 0, 0, 0);
    acc = __builtin_amdgcn_mfma_f32_16x16x32_f16(al, bh, acc, 0, 0, 0);
    acc = __builtin_amdgcn_mfma_f32_16x16x32_f16(ah, bl, acc, 0, 0, 0);
}

// 1-term: f16 activation x f16 weight (hi only) — 0.0678 absmax budget covers rounding
__device__ __forceinline__ void mfma1(f32x4& acc, f16x8 ah, f16x8 bh)
{
    acc = __builtin_amdgcn_mfma_f32_16x16x32_f16(ah, bh, acc, 0, 0, 0);
}

// load this wave's packed B-frags (hi plane only) for one 32-K w2/w3 chunk into slot s.
// bH is a wave-uniform runtime base.
#define FETCH_BPD(bH, kc, s) do {                                            \
    _Pragma("unroll")                                                        \
    for (int _nt = 0; _nt < 4; ++_nt) {                                      \
        int _off = (kc)*8192 + (q*256 + 64*cw + 16*_nt + lr)*8;              \
        FH[s][_nt] = *(const f16x8*)(wp + (bH) + _off);                      \
    }                                                                        \
} while (0)

// dedicated w1 slot (single 32-K chunk; hi+lo, exact)
#define FETCH_W1() do {                                                      \
    _Pragma("unroll")                                                        \
    for (int _nt = 0; _nt < 4; ++_nt) {                                      \
        int _off = (q*256 + 64*cw + 16*_nt + lr)*8;                          \
        WH[_nt] = *(const f16x8*)(wp + W1H + _off);                          \
        WL[_nt] = *(const f16x8*)(wp + W1L + _off);                          \
    }                                                                        \
} while (0)

// one K-chunk: this wave's 64-row half x 64 cols; 4 ds_read_b128 per 16 MFMA
#define GEMM_CHUNK(s, kcl) do {                                              \
    _Pragma("unroll")                                                        \
    for (int _mt = 0; _mt < 4; ++_mt) {                                      \
        int _row = 64*rh + 16*_mt + lr;                                      \
        int _off = _row*256 + ((((kcl)*4 + q) ^ (_row & 31)) << 3);          \
        f16x8 _ah = *(const f16x8*)(hA_hi + _off);                           \
        _Pragma("unroll")                                                    \
        for (int _nt = 0; _nt < 4; ++_nt)                                    \
            mfma1(acc[_mt][_nt], _ah, FH[s][_nt]);                           \
    }                                                                        \
} while (0)

// relu + f16 round, hi plane only
#define WRITEBACK_ACC() do {                                                 \
    _Pragma("unroll")                                                        \
    for (int _mt = 0; _mt < 4; ++_mt)                                        \
      _Pragma("unroll")                                                      \
      for (int _nt = 0; _nt < 4; ++_nt)                                      \
        _Pragma("unroll")                                                    \
        for (int _r = 0; _r < 4; ++_r) {                                     \
            float _h = fmaxf(acc[_mt][_nt][_r], 0.f);                        \
            int _row = 64*rh + 16*_mt + 4*q + _r;                            \
            int _col = 64*cw + 16*_nt + lr;                                  \
            int _off = _row*256 + (((_col >> 3) ^ (_row & 31)) << 3) + (_col & 7); \
            hA_hi[_off] = (f16)_h;                                           \
        }                                                                    \
} while (0)

#define INIT_ACC(brv) do {                                                   \
    _Pragma("unroll")                                                        \
    for (int _mt = 0; _mt < 4; ++_mt)                                        \
      _Pragma("unroll")                                                      \
      for (int _nt = 0; _nt < 4; ++_nt)                                      \
        acc[_mt][_nt] = (f32x4){(brv)[_nt], (brv)[_nt], (brv)[_nt], (brv)[_nt]}; \
} while (0)

// obs write: hi plane -> hA_hi, lo plane -> oLo (obs x w1 stays fp32-exact)
#define OBS_WRITE() do {                                                     \
    float _dx0 = px - 1.75f, _dy0 = py - 1.75f;                              \
    float _dx1 = px - 1.75f, _dy1 = py - 3.75f;                              \
    float _dx2 = px - 3.75f, _dy2 = py - 2.00f;                              \
    float _v[8];                                                             \
    f16x8 _hi, _lo;                                                          \
    _v[0] = px*0.1f;        _v[1] = py*0.1f;                                 \
    _v[2] = (4.f-px)*0.1f;  _v[3] = (3.f-py)*0.1f;                           \
    _v[4] = -_dx0*0.1f;     _v[5] = -_dy0*0.1f;                              \
    _v[6] = -_dx1*0.1f;     _v[7] = -_dy1*0.1f;                              \
    _Pragma("unroll")                                                        \
    for (int _j = 0; _j < 8; ++_j) {                                         \
        f16 _h = (f16)_v[_j];                                                \
        _hi[_j] = _h; _lo[_j] = (f16)(_v[_j] - (float)_h);                   \
    }                                                                        \
    *(f16x8*)(hA_hi + t*40)     = _hi;                                       \
    *(f16x8*)(oLo   + t*40)     = _lo;                                       \
    _v[0] = -_dx2*0.1f;     _v[1] = -_dy2*0.1f;                              \
    _v[2] = sqrtf(_dx0*_dx0+_dy0*_dy0+1e-9f) - 0.38f;                        \
    _v[3] = sqrtf(_dx1*_dx1+_dy1*_dy1+1e-9f) - 0.42f;                        \
    _v[4] = sqrtf(_dx2*_dx2+_dy2*_dy2+1e-9f) - 0.34f;                        \
    _v[5] = 0.f; _v[6] = 0.f; _v[7] = 0.f;                                   \
    _Pragma("unroll")                                                        \
    for (int _j = 0; _j < 8; ++_j) {                                         \
        f16 _h = (f16)_v[_j];                                                \
        _hi[_j] = _h; _lo[_j] = (f16)(_v[_j] - (float)_h);                   \
    }                                                                        \
    *(f16x8*)(hA_hi + t*40 + 8) = _hi;                                       \
    *(f16x8*)(oLo   + t*40 + 8) = _lo;                                       \
    f16x8 _z;                                                                \
    _Pragma("unroll")                                                        \
    for (int _j = 0; _j < 8; ++_j) _z[_j] = (f16)0.f;                        \
    *(f16x8*)(hA_hi + t*40 + 16) = _z;                                       \
    *(f16x8*)(oLo   + t*40 + 16) = _z;                                       \
    *(f16x8*)(hA_hi + t*40 + 24) = _z;                                       \
    *(f16x8*)(oLo   + t*40 + 24) = _z;                                       \
} while (0)

__global__ __launch_bounds__(NT, 2)   // 256 arch regs/wave (proven spill-free regime)
void rollout_kernel(const float* __restrict__ pos0, const float* __restrict__ wind,
                    const float* __restrict__ b1, const float* __restrict__ b2,
                    const float* __restrict__ b3, const float* __restrict__ wmu,
                    const float* __restrict__ bmu, const f16* __restrict__ wp,
                    float* __restrict__ out)
{
    // activations f16 (hi only), XOR-chunk swizzle: (row,k)->row*256+((k>>3 ^ (row&31))<<3)+(k&7)
    __shared__ __align__(16) f16 hA_hi[M*256];   // 64 KB
    __shared__ __align__(16) f16 oLo[M*40];      // 10 KB obs residual plane
    __shared__ __align__(16) float paL[2*M];     // 1 KB final action partials -> 75 KB total

    const int t  = threadIdx.x;
    const int l  = t & 63;
    const int wv = t >> 6;         // wave id 0..7
    const int rh = wv >> 2;        // GEMM row half: rows [64rh, 64rh+64)
    const int cw = wv & 3;         // GEMM col quarter: cols [64cw, 64cw+64)
    const int lr = l & 15;
    const int q  = l >> 4;

    float b1r[4], b2r[4], b3r[4];
    #pragma unroll
    for (int nt = 0; nt < 4; ++nt) {
        int col = 64*cw + 16*nt + lr;
        b1r[nt] = b1[col]; b2r[nt] = b2[col]; b3r[nt] = b3[col];
    }
    const float bm0 = bmu[0], bm1 = bmu[1];

    // wmu packed into MFMA B-fragment layout (hi only): B[k][n] for k=q*8+j within chunk kc,
    // col n = lr (only n<2 nonzero). Loaded once; 32 regs. L4 rows come from wave id wv.
    f16x8 WM[8];
    #pragma unroll
    for (int kc = 0; kc < 8; ++kc)
        #pragma unroll
        for (int j = 0; j < 8; ++j)
            WM[kc][j] = (lr < 2) ? (f16)wmu[2*(kc*32 + q*8 + j) + lr] : (f16)0.f;

    float px=0.f, py=0.f, wx=0.f, wy=0.f;
    float mx_s=-1e30f, sum_s=0.f, mx_r=-1e30f, sum_r=0.f;
    if (t < M) {
        int g = blockIdx.x*M + t;
        px = pos0[2*g]; py = pos0[2*g+1]; wx = wind[2*g]; wy = wind[2*g+1];
    }

    f16x8 FH[2][4];             // 2 rotating stream slots x 4 nt (hi plane only): 32 regs
    f16x8 WH[4], WL[4];         // dedicated w1 slot (exact): 32 regs
    f32x4 acc[4][4];            // 64 accumulator regs (AGPR-eligible)

    // ---- priming: w1 + stream chunks 0,1 (w2 kc0,kc1) ----
    FETCH_W1();
    FETCH_BPD(W2H, 0, 0);
    FETCH_BPD(W2H, 1, 1);
    if (t < M) { OBS_WRITE(); }

    #pragma unroll 1
    for (int step = 0; step < HORIZON; ++step) {
        __syncthreads();   // B1: obs visible

        // ---- L1: obs(13 pad 32) x w1 (dedicated slot), full 3-term precision ----
        INIT_ACC(b1r);
        #pragma unroll
        for (int mt = 0; mt < 4; ++mt) {
            int off = (64*rh + 16*mt + lr)*40 + q*8;
            f16x8 ah = *(const f16x8*)(hA_hi + off);
            f16x8 al = *(const f16x8*)(oLo   + off);
            #pragma unroll
            for (int nt = 0; nt < 4; ++nt)
                mfma3(acc[mt][nt], ah, al, WH[nt], WL[nt]);
        }
        __syncthreads();   // B2: obs reads done -> hA writable
        WRITEBACK_ACC();   // h1 -> hA
        INIT_ACC(b2r);
        __syncthreads();   // B3: h1 visible

        // ---- h1 x w2: chunks 0..7, rolled pair-loop (I-cache diet) ----
        // fetch target chunk j = g+2: j<8 -> w2 kc=j ; j>=8 -> w3 kc=j-8
        #pragma unroll 1
        for (int gp = 0; gp < 8; gp += 2) {
            GEMM_CHUNK(0, gp);
            { int j = gp + 2; int bH = (j & 8) ? W3H : W2H; FETCH_BPD(bH, j & 7, 0); }
            GEMM_CHUNK(1, gp + 1);
            { int j = gp + 3; int bH = (j & 8) ? W3H : W2H; FETCH_BPD(bH, j & 7, 1); }
        }
        __syncthreads();   // B4: h1 reads done
        WRITEBACK_ACC();   // h2 -> hA
        INIT_ACC(b3r);
        __syncthreads();   // B5: h2 visible
        FETCH_W1();        // next-step w1 (8 chunks of cover)

        // ---- h2 x w3: chunks 8..15; fetch j=g+2 (10..15 w3; 16,17 -> next-step w2 kc0,1) ----
        #pragma unroll 1
        for (int gp = 8; gp < 16; gp += 2) {
            GEMM_CHUNK(0, gp - 8);
            { int j = gp + 2; int bH = (j & 8) ? W3H : W2H; FETCH_BPD(bH, j & 7, 0); }
            GEMM_CHUNK(1, gp - 7);
            { int j = gp + 3; int bH = (j & 8) ? W3H : W2H; FETCH_BPD(bH, j & 7, 1); }
        }

        // ---- L4 via MFMA matvec: h3 -> hA, then out[16x2] = h3[16x256] x wmuB ----
        __syncthreads();   // B6: h2 reads done -> hA writable
        WRITEBACK_ACC();   // h3 -> hA (relu'd f16)
        __syncthreads();   // B7: h3 visible
        {
            f32x4 aL4 = (f32x4){0.f, 0.f, 0.f, 0.f};
            int row = 16*wv + lr;   // this wave owns output rows [16wv,16wv+16)
            #pragma unroll
            for (int kc = 0; kc < 8; ++kc) {
                int off = row*256 + (((kc*4 + q) ^ (row & 31)) << 3);
                f16x8 a3 = *(const f16x8*)(hA_hi + off);
                aL4 = __builtin_amdgcn_mfma_f32_16x16x32_f16(a3, WM[kc], aL4, 0, 0, 0);
            }
            if (lr < 2) {   // C layout: lane(q,lr) reg r = out[16wv+4q+r][lr]
                #pragma unroll
                for (int r = 0; r < 4; ++r)
                    paL[lr*M + 16*wv + 4*q + r] = aL4[r];
            }
        }
        __syncthreads();   // B8: paL visible; hA L4-reads done -> OBS_WRITE safe

        // ---- P5 + P0: action, dynamics, STREL, next obs (threads 0..127) ----
        if (t < M) {
            float s0 = bm0 + paL[t];
            float s1 = bm1 + paL[M + t];
            float ax = fminf(fmaxf(s0, -1.f), 1.f);
            float ay = fminf(fmaxf(s1, -1.f), 1.f);
            float vx = 2.f*ax + wx, vy = 2.f*ay + wy;
            #pragma unroll
            for (int s = 0; s < 4; ++s) {
                px = fminf(fmaxf(px + 0.0625f*vx, -4.f), 10.f);
                py = fminf(fmaxf(py + 0.0625f*vy, -4.f), 10.f);
            }
            float dx0 = px - 1.75f, dy0 = py - 1.75f;
            float dx1 = px - 1.75f, dy1 = py - 3.75f;
            float dx2 = px - 3.75f, dy2 = py - 2.00f;
            float c0 = sqrtf(dx0*dx0+dy0*dy0+1e-9f) - 0.38f;
            float c1 = sqrtf(dx1*dx1+dy1*dy1+1e-9f) - 0.42f;
            float c2 = sqrtf(dx2*dx2+dy2*dy2+1e-9f) - 0.34f;
            float cmin = fminf(c0, fminf(c1, c2));
            float ssum = expf(-50.f*(c0-cmin)) + expf(-50.f*(c1-cmin)) + expf(-50.f*(c2-cmin));
            float safe = cmin - logf(ssum)/50.f;
            float gdx = px - 4.f, gdy = py - 3.f;
            float reach = 0.45f - sqrtf(gdx*gdx+gdy*gdy+1e-9f);
            float xs = -8.f*safe;
            if (xs > mx_s) { sum_s = sum_s*expf(mx_s - xs) + 1.f; mx_s = xs; }
            else           { sum_s += expf(xs - mx_s); }
            float xr = 8.f*reach;
            if (xr > mx_r) { sum_r = sum_r*expf(mx_r - xr) + 1.f; mx_r = xr; }
            else           { sum_r += expf(xr - mx_r); }
            OBS_WRITE();   // obs for next step
        }
    }

    if (t < M) {
        float rs = -(mx_s + logf(sum_s)) * 0.125f;
        float rr =  (mx_r + logf(sum_r)) * 0.125f;
        float u0 = -8.f*rs, u1 = -8.f*rr;
        float mu = fmaxf(u0, u1);
        float rho = -(mu + logf(expf(u0-mu) + expf(u1-mu))) * 0.125f;
        out[blockIdx.x*M + t] = rho;
    }
}

} // namespace

extern "C" void kernel_launch(void* const* d_in, const int* in_sizes, int n_in,
                              void* d_out, int out_size, void* d_ws, size_t ws_size,
                              hipStream_t stream)
{
    const float* pos0 = (const float*)d_in[0];
    const float* wind = (const float*)d_in[1];
    const float* w1   = (const float*)d_in[2];
    const float* b1   = (const float*)d_in[3];
    const float* w2   = (const float*)d_in[4];
    const float* b2   = (const float*)d_in[5];
    const float* w3   = (const float*)d_in[6];
    const float* b3   = (const float*)d_in[7];
    const float* wmu  = (const float*)d_in[8];
    const float* bmu  = (const float*)d_in[9];
    float* out = (float*)d_out;
    f16* wp = (f16*)d_ws;   // 278528 f16 = 544 KB packed weights

    prep_kernel<<<544, 256, 0, stream>>>(w1, w2, w3, wp);

    const int B = in_sizes[0] / 2;     // 32768 agents
    const int blocks = B / M;          // 256 blocks of 512 threads = 1 per CU, single pass
    rollout_kernel<<<blocks, NT, 0, stream>>>(pos0, wind, b1, b2, b3,
                                              wmu, bmu, wp, out);
}

// Round 16
// 722.931 us; speedup vs baseline: 1.1532x; 1.1532x over previous
//
#include <hip/hip_runtime.h>
#include <math.h>

typedef _Float16 f16;
typedef _Float16 f16x8 __attribute__((ext_vector_type(8)));
typedef float f32x4 __attribute__((ext_vector_type(4)));

namespace {

constexpr int NT = 512;     // 8 waves, each 128 rows x 32 cols; M=128 rows (r14 tiling)
constexpr int M  = 128;     // agents per block: 256 blocks = 1 per CU, single pass
constexpr int HORIZON = 64;

// packed f16 weight layout in d_ws (f16 units); per-chunk fragment order [q][col][j]
constexpr int W2H = 0;        // 65536 f16
constexpr int W2L = 65536;
constexpr int W3H = 131072;
constexpr int W3L = 196608;
constexpr int W1H = 262144;   // 8192 f16 (K padded 13->32)
constexpr int W1L = 270336;   // total 278528 f16 = 544 KB

// ---------------- weight pre-pack (once per launch) ----------------
__global__ void prep_kernel(const float* __restrict__ w1, const float* __restrict__ w2,
                            const float* __restrict__ w3, f16* __restrict__ out)
{
    int tid = blockIdx.x * blockDim.x + threadIdx.x;   // 544*256 = 139264 exact
    float v; int hi, lo;
    if (tid < 65536) {          // w2
        int kc = tid >> 13, e2 = tid & 8191;
        int qq = e2 >> 11, col = (e2 >> 3) & 255, j = e2 & 7;
        v = w2[(kc*32 + qq*8 + j)*256 + col];
        hi = W2H + tid; lo = W2L + tid;
    } else if (tid < 131072) {  // w3
        int e = tid - 65536;
        int kc = e >> 13, e2 = e & 8191;
        int qq = e2 >> 11, col = (e2 >> 3) & 255, j = e2 & 7;
        v = w3[(kc*32 + qq*8 + j)*256 + col];
        hi = W3H + e; lo = W3L + e;
    } else {                    // w1, zero-padded to k=32
        int e = tid - 131072;
        int qq = e >> 11, col = (e >> 3) & 255, j = e & 7;
        int k = qq*8 + j;
        v = (k < 13) ? w1[k*256 + col] : 0.f;
        hi = W1H + e; lo = W1L + e;
    }
    f16 h = (f16)v;
    out[hi] = h;
    out[lo] = (f16)(v - (float)h);   // residual planes retained in ws (unused now)
}

// 1-term: f16 x f16 — 0.0678 absmax budget covers rounding everywhere
__device__ __forceinline__ void mfma1(f32x4& acc, f16x8 ah, f16x8 bh)
{
    acc = __builtin_amdgcn_mfma_f32_16x16x32_f16(ah, bh, acc, 0, 0, 0);
}

// load this wave's packed B-frag (hi plane only) for one 32-K w2/w3 chunk into slot s.
// bH is a wave-uniform runtime base.
#define FETCH_BPD(bH, kc, s) do {                                            \
    _Pragma("unroll")                                                        \
    for (int _nt = 0; _nt < 2; ++_nt) {                                      \
        int _off = (kc)*8192 + (q*256 + 32*cq + 16*_nt + lr)*8;              \
        FH[s][_nt] = *(const f16x8*)(wp + (bH) + _off);                      \
    }                                                                        \
} while (0)

// dedicated w1 slot (single 32-K chunk; hi plane only)
#define FETCH_W1() do {                                                      \
    _Pragma("unroll")                                                        \
    for (int _nt = 0; _nt < 2; ++_nt) {                                      \
        int _off = (q*256 + 32*cq + 16*_nt + lr)*8;                          \
        WH[_nt] = *(const f16x8*)(wp + W1H + _off);                          \
    }                                                                        \
} while (0)

// one K-chunk: f16 activations x f16 weights; 8 ds_read_b128 per 16 MFMA
#define GEMM_CHUNK(s, kcl) do {                                              \
    _Pragma("unroll")                                                        \
    for (int _mt = 0; _mt < 8; ++_mt) {                                      \
        int _row = 16*_mt + lr;                                              \
        int _off = _row*256 + ((((kcl)*4 + q) ^ (_row & 31)) << 3);          \
        f16x8 _ah = *(const f16x8*)(hA_hi + _off);                           \
        _Pragma("unroll")                                                    \
        for (int _nt = 0; _nt < 2; ++_nt)                                    \
            mfma1(acc[_mt][_nt], _ah, FH[s][_nt]);                           \
    }                                                                        \
} while (0)

// relu + f16 round, hi plane only
#define WRITEBACK_ACC() do {                                                 \
    _Pragma("unroll")                                                        \
    for (int _mt = 0; _mt < 8; ++_mt)                                        \
      _Pragma("unroll")                                                      \
      for (int _nt = 0; _nt < 2; ++_nt)                                      \
        _Pragma("unroll")                                                    \
        for (int _r = 0; _r < 4; ++_r) {                                     \
            float _h = fmaxf(acc[_mt][_nt][_r], 0.f);                        \
            int _row = 16*_mt + 4*q + _r;                                    \
            int _col = 32*cq + 16*_nt + lr;                                  \
            int _off = _row*256 + (((_col >> 3) ^ (_row & 31)) << 3) + (_col & 7); \
            hA_hi[_off] = (f16)_h;                                           \
        }                                                                    \
} while (0)

#define INIT_ACC(brv) do {                                                   \
    _Pragma("unroll")                                                        \
    for (int _mt = 0; _mt < 8; ++_mt)                                        \
      _Pragma("unroll")                                                      \
      for (int _nt = 0; _nt < 2; ++_nt)                                      \
        acc[_mt][_nt] = (f32x4){(brv)[_nt], (brv)[_nt], (brv)[_nt], (brv)[_nt]}; \
} while (0)

// obs write: f16 hi plane only into hA_hi (t*40 layout, k 0..31 incl zero pad)
#define OBS_WRITE() do {                                                     \
    float _dx0 = px - 1.75f, _dy0 = py - 1.75f;                              \
    float _dx1 = px - 1.75f, _dy1 = py - 3.75f;                              \
    float _dx2 = px - 3.75f, _dy2 = py - 2.00f;                              \
    float _v[8];                                                             \
    f16x8 _h8;                                                               \
    _v[0] = px*0.1f;        _v[1] = py*0.1f;                                 \
    _v[2] = (4.f-px)*0.1f;  _v[3] = (3.f-py)*0.1f;                           \
    _v[4] = -_dx0*0.1f;     _v[5] = -_dy0*0.1f;                              \
    _v[6] = -_dx1*0.1f;     _v[7] = -_dy1*0.1f;                              \
    _Pragma("unroll")                                                        \
    for (int _j = 0; _j < 8; ++_j) _h8[_j] = (f16)_v[_j];                    \
    *(f16x8*)(hA_hi + t*40)     = _h8;                                       \
    _v[0] = -_dx2*0.1f;     _v[1] = -_dy2*0.1f;                              \
    _v[2] = sqrtf(_dx0*_dx0+_dy0*_dy0+1e-9f) - 0.38f;                        \
    _v[3] = sqrtf(_dx1*_dx1+_dy1*_dy1+1e-9f) - 0.42f;                        \
    _v[4] = sqrtf(_dx2*_dx2+_dy2*_dy2+1e-9f) - 0.34f;                        \
    _v[5] = 0.f; _v[6] = 0.f; _v[7] = 0.f;                                   \
    _Pragma("unroll")                                                        \
    for (int _j = 0; _j < 8; ++_j) _h8[_j] = (f16)_v[_j];                    \
    *(f16x8*)(hA_hi + t*40 + 8) = _h8;                                       \
    f16x8 _z;                                                                \
    _Pragma("unroll")                                                        \
    for (int _j = 0; _j < 8; ++_j) _z[_j] = (f16)0.f;                        \
    *(f16x8*)(hA_hi + t*40 + 16) = _z;                                       \
    *(f16x8*)(hA_hi + t*40 + 24) = _z;                                       \
} while (0)

__global__ __launch_bounds__(NT, 2)   // 256 arch regs/wave (proven spill-free regime)
void rollout_kernel(const float* __restrict__ pos0, const float* __restrict__ wind,
                    const float* __restrict__ b1, const float* __restrict__ b2,
                    const float* __restrict__ b3, const float* __restrict__ wmu,
                    const float* __restrict__ bmu, const f16* __restrict__ wp,
                    float* __restrict__ out)
{
    // activations f16 (hi only), XOR-chunk swizzle: (row,k)->row*256+((k>>3 ^ (row&31))<<3)+(k&7)
    __shared__ __align__(16) f16 hA_hi[M*256];   // 64 KB
    __shared__ __align__(16) float paL[2*M];     // 1 KB final action partials -> 65 KB total

    const int t  = threadIdx.x;
    const int l  = t & 63;
    const int cq = t >> 6;         // wave id 0..7: GEMM cols [32cq,32cq+32); L4 rows [16cq,16cq+16)
    const int lr = l & 15;
    const int q  = l >> 4;

    float b1r[2], b2r[2], b3r[2];
    #pragma unroll
    for (int nt = 0; nt < 2; ++nt) {
        int col = 32*cq + 16*nt + lr;
        b1r[nt] = b1[col]; b2r[nt] = b2[col]; b3r[nt] = b3[col];
    }
    const float bm0 = bmu[0], bm1 = bmu[1];

    // wmu packed into MFMA B-fragment layout (hi only): B[k][n] for k=q*8+j within chunk kc,
    // col n = lr (only n<2 nonzero). Loaded once; 32 VGPRs.
    f16x8 WM[8];
    #pragma unroll
    for (int kc = 0; kc < 8; ++kc)
        #pragma unroll
        for (int j = 0; j < 8; ++j)
            WM[kc][j] = (lr < 2) ? (f16)wmu[2*(kc*32 + q*8 + j) + lr] : (f16)0.f;

    float px=0.f, py=0.f, wx=0.f, wy=0.f;
    float mx_s=-1e30f, sum_s=0.f, mx_r=-1e30f, sum_r=0.f;
    if (t < M) {
        int g = blockIdx.x*M + t;
        px = pos0[2*g]; py = pos0[2*g+1]; wx = wind[2*g]; wy = wind[2*g+1];
    }

    f16x8 FH[2][2];             // 2 rotating stream slots (hi plane only): 16 regs
    f16x8 WH[2];                // dedicated w1 slot (hi plane only): 8 regs
    f32x4 acc[8][2];            // 64 accumulator regs (AGPR-eligible)

    // ---- priming: w1 + stream chunks 0,1 (w2 kc0,kc1) ----
    FETCH_W1();
    FETCH_BPD(W2H, 0, 0);
    FETCH_BPD(W2H, 1, 1);
    if (t < M) { OBS_WRITE(); }

    #pragma unroll 1
    for (int step = 0; step < HORIZON; ++step) {
        __syncthreads();   // B1: obs visible

        // ---- L1: obs(13 pad 32) x w1 (dedicated slot), 1-term f16 ----
        INIT_ACC(b1r);
        #pragma unroll
        for (int mt = 0; mt < 8; ++mt) {
            int off = (16*mt + lr)*40 + q*8;
            f16x8 ah = *(const f16x8*)(hA_hi + off);
            #pragma unroll
            for (int nt = 0; nt < 2; ++nt)
                mfma1(acc[mt][nt], ah, WH[nt]);
        }
        __syncthreads();   // B2: obs reads done -> hA writable
        WRITEBACK_ACC();   // h1 -> hA
        INIT_ACC(b2r);
        __syncthreads();   // B3: h1 visible

        // ---- h1 x w2: chunks 0..7, rolled pair-loop (I-cache diet) ----
        // fetch target chunk j = g+2: j<8 -> w2 kc=j ; j>=8 -> w3 kc=j-8
        #pragma unroll 1
        for (int gp = 0; gp < 8; gp += 2) {
            GEMM_CHUNK(0, gp);
            { int j = gp + 2; int bH = (j & 8) ? W3H : W2H; FETCH_BPD(bH, j & 7, 0); }
            GEMM_CHUNK(1, gp + 1);
            { int j = gp + 3; int bH = (j & 8) ? W3H : W2H; FETCH_BPD(bH, j & 7, 1); }
        }
        __syncthreads();   // B4: h1 reads done
        WRITEBACK_ACC();   // h2 -> hA
        INIT_ACC(b3r);
        __syncthreads();   // B5: h2 visible
        FETCH_W1();        // next-step w1 (8 chunks of cover)

        // ---- h2 x w3: chunks 8..15; fetch j=g+2 (10..15 w3; 16,17 -> next-step w2 kc0,1) ----
        #pragma unroll 1
        for (int gp = 8; gp < 16; gp += 2) {
            GEMM_CHUNK(0, gp - 8);
            { int j = gp + 2; int bH = (j & 8) ? W3H : W2H; FETCH_BPD(bH, j & 7, 0); }
            GEMM_CHUNK(1, gp - 7);
            { int j = gp + 3; int bH = (j & 8) ? W3H : W2H; FETCH_BPD(bH, j & 7, 1); }
        }

        // ---- L4 via MFMA matvec: h3 -> hA, then out[16x2] = h3[16x256] x wmuB ----
        __syncthreads();   // B6: h2 reads done -> hA writable
        WRITEBACK_ACC();   // h3 -> hA (relu'd f16)
        __syncthreads();   // B7: h3 visible
        {
            f32x4 aL4 = (f32x4){0.f, 0.f, 0.f, 0.f};
            int row = 16*cq + lr;   // this wave owns output rows [16cq,16cq+16)
            #pragma unroll
            for (int kc = 0; kc < 8; ++kc) {
                int off = row*256 + (((kc*4 + q) ^ (row & 31)) << 3);
                f16x8 a3 = *(const f16x8*)(hA_hi + off);
                aL4 = __builtin_amdgcn_mfma_f32_16x16x32_f16(a3, WM[kc], aL4, 0, 0, 0);
            }
            if (lr < 2) {   // C layout: lane(q,lr) reg r = out[16cq+4q+r][lr]
                #pragma unroll
                for (int r = 0; r < 4; ++r)
                    paL[lr*M + 16*cq + 4*q + r] = aL4[r];
            }
        }
        __syncthreads();   // B8: paL visible; hA L4-reads done -> OBS_WRITE safe

        // ---- P5 + P0: action, dynamics, STREL, next obs (threads 0..127) ----
        if (t < M) {
            float s0 = bm0 + paL[t];
            float s1 = bm1 + paL[M + t];
            float ax = fminf(fmaxf(s0, -1.f), 1.f);
            float ay = fminf(fmaxf(s1, -1.f), 1.f);
            float vx = 2.f*ax + wx, vy = 2.f*ay + wy;
            #pragma unroll
            for (int s = 0; s < 4; ++s) {
                px = fminf(fmaxf(px + 0.0625f*vx, -4.f), 10.f);
                py = fminf(fmaxf(py + 0.0625f*vy, -4.f), 10.f);
            }
            float dx0 = px - 1.75f, dy0 = py - 1.75f;
            float dx1 = px - 1.75f, dy1 = py - 3.75f;
            float dx2 = px - 3.75f, dy2 = py - 2.00f;
            float c0 = sqrtf(dx0*dx0+dy0*dy0+1e-9f) - 0.38f;
            float c1 = sqrtf(dx1*dx1+dy1*dy1+1e-9f) - 0.42f;
            float c2 = sqrtf(dx2*dx2+dy2*dy2+1e-9f) - 0.34f;
            float cmin = fminf(c0, fminf(c1, c2));
            float ssum = expf(-50.f*(c0-cmin)) + expf(-50.f*(c1-cmin)) + expf(-50.f*(c2-cmin));
            float safe = cmin - logf(ssum)/50.f;
            float gdx = px - 4.f, gdy = py - 3.f;
            float reach = 0.45f - sqrtf(gdx*gdx+gdy*gdy+1e-9f);
            float xs = -8.f*safe;
            if (xs > mx_s) { sum_s = sum_s*expf(mx_s - xs) + 1.f; mx_s = xs; }
            else           { sum_s += expf(xs - mx_s); }
            float xr = 8.f*reach;
            if (xr > mx_r) { sum_r = sum_r*expf(mx_r - xr) + 1.f; mx_r = xr; }
            else           { sum_r += expf(xr - mx_r); }
            OBS_WRITE();   // obs for next step
        }
    }

    if (t < M) {
        float rs = -(mx_s + logf(sum_s)) * 0.125f;
        float rr =  (mx_r + logf(sum_r)) * 0.125f;
        float u0 = -8.f*rs, u1 = -8.f*rr;
        float mu = fmaxf(u0, u1);
        float rho = -(mu + logf(expf(u0-mu) + expf(u1-mu))) * 0.125f;
        out[blockIdx.x*M + t] = rho;
    }
}

} // namespace

extern "C" void kernel_launch(void* const* d_in, const int* in_sizes, int n_in,
                              void* d_out, int out_size, void* d_ws, size_t ws_size,
                              hipStream_t stream)
{
    const float* pos0 = (const float*)d_in[0];
    const float* wind = (const float*)d_in[1];
    const float* w1   = (const float*)d_in[2];
    const float* b1   = (const float*)d_in[3];
    const float* w2   = (const float*)d_in[4];
    const float* b2   = (const float*)d_in[5];
    const float* w3   = (const float*)d_in[6];
    const float* b3   = (const float*)d_in[7];
    const float* wmu  = (const float*)d_in[8];
    const float* bmu  = (const float*)d_in[9];
    float* out = (float*)d_out;
    f16* wp = (f16*)d_ws;   // 278528 f16 = 544 KB packed weights

    prep_kernel<<<544, 256, 0, stream>>>(w1, w2, w3, wp);

    const int B = in_sizes[0] / 2;     // 32768 agents
    const int blocks = B / M;          // 256 blocks of 512 threads = 1 per CU, single pass
    rollout_kernel<<<blocks, NT, 0, stream>>>(pos0, wind, b1, b2, b3,
                                              wmu, bmu, wp, out);
}